// Round 5
// baseline (97.725 us; speedup 1.0000x reference)
//
#include <hip/hip_runtime.h>
#include <hip/hip_bf16.h>
#include <cstdint>

// Problem constants
#define Bn 8
#define Cn 64
#define Hn 112
#define Wn 112
#define On 64
#define Ln (Hn * Wn)   // 12544 = 98 * 128
#define HP 114
#define WP 114

typedef __attribute__((ext_vector_type(4)))  float f32x4;
typedef __attribute__((ext_vector_type(16))) float f32x16;
typedef __attribute__((ext_vector_type(8)))  short bf16x8;
typedef __attribute__((ext_vector_type(4)))  unsigned int u32x4;

typedef __attribute__((address_space(3))) unsigned int lds_u32;
typedef __attribute__((address_space(1))) const unsigned int glob_u32;

__device__ __forceinline__ unsigned f2bf(float f) {
    unsigned u = __float_as_uint(f);
    unsigned r = 0x7fffu + ((u >> 16) & 1u);
    return (u + r) >> 16;   // RNE bf16 in low 16 bits
}

// -----------------------------------------------------------------------------
// Kernel 1 (fused prep):
//  blocks [0,912):  x [B][C][112][112] f32 -> xps: padded NHWC bf16 with the
//    LDS slot-permutation PRE-APPLIED in global memory:
//      chunk addr = ((b*114 + row)*114 + wp)*8 + (c8 ^ (wp & 7)),  16B chunks
//    (c8 = channel-octet). conv then uses global_load_lds into LINEAR LDS and
//    reads with the matching XOR — both-sides swizzle via pre-swizzled source.
//  blocks [912,948): weight [O][C][3][3] f32 -> wpk bf16 A-fragments for
//    v_mfma_f32_32x32x16_bf16: fidx=(p*2+wr)*4+kc; lane: o=wr*32+(lane&31),
//    c=kc*16+(lane>>5)*8+j.
// -----------------------------------------------------------------------------
__global__ __launch_bounds__(128) void prep_kernel(const float* __restrict__ x,
                                                   const float* __restrict__ w,
                                                   unsigned short* __restrict__ xps,
                                                   unsigned short* __restrict__ wpk) {
    int blk = blockIdx.x;
    int t = threadIdx.x;
    if (blk < 912) {
        int b = blk / HP, row = blk - b * HP;   // padded row index
        int c8  = t >> 4;                       // 0..7 channel octet
        int wpl = t & 15;
        int h = row - 1;                        // input row
        const float* xb = x + (size_t)b * Cn * Hn * Wn;
        unsigned short* dst = xps + ((size_t)(b * HP + row) * WP) * Cn;
#pragma unroll
        for (int g = 0; g < 8; ++g) {
            int wp = wpl + (g << 4);
            if (wp < WP) {
                int wcol = wp - 1;
                bool inb = ((unsigned)h < (unsigned)Hn) & ((unsigned)wcol < (unsigned)Wn);
                const float* s = xb + ((size_t)(c8 * 8) * Hn + (inb ? h : 0)) * Wn + (inb ? wcol : 0);
                unsigned pk[4];
#pragma unroll
                for (int j = 0; j < 4; ++j) {
                    float v0 = s[(size_t)(2 * j)     * (Hn * Wn)];
                    float v1 = s[(size_t)(2 * j + 1) * (Hn * Wn)];
                    if (!inb) { v0 = 0.f; v1 = 0.f; }
                    pk[j] = f2bf(v0) | (f2bf(v1) << 16);
                }
                int slot = c8 ^ (wp & 7);       // pre-applied swizzle
                u32x4 v; v[0] = pk[0]; v[1] = pk[1]; v[2] = pk[2]; v[3] = pk[3];
                *reinterpret_cast<u32x4*>(dst + ((size_t)wp * 8 + slot) * 8) = v;
            }
        }
    } else {
        int idx = (blk - 912) * 2 + (t >> 6);   // 0..71 = (p*2+wr)*4+kc
        int lane = t & 63;
        int kc = idx & 3, wr2 = (idx >> 2) & 1, p = idx >> 3;
        int o  = wr2 * 32 + (lane & 31);
        int cb = kc * 16 + (lane >> 5) * 8;
        unsigned pk[4];
#pragma unroll
        for (int j = 0; j < 4; ++j) {
            float v0 = w[((size_t)o * Cn + cb + 2 * j) * 9 + p];
            float v1 = w[((size_t)o * Cn + cb + 2 * j + 1) * 9 + p];
            pk[j] = f2bf(v0) | (f2bf(v1) << 16);
        }
        u32x4 v; v[0] = pk[0]; v[1] = pk[1]; v[2] = pk[2]; v[3] = pk[3];
        reinterpret_cast<u32x4*>(wpk)[idx * 64 + lane] = v;
    }
}

// -----------------------------------------------------------------------------
// Kernel 2: implicit-GEMM conv, 32x32x16 MFMA, per-pixel tap mask.
// Block = 512 thr (8 waves: 2(O) x 4(pixel)), 128 consecutive pixels x 64 o
// of one image. Stages 4 pre-swizzled padded bf16 rows (58368 B) via
// global_load_lds dwordx4 into LINEAR LDS (zero staging VALU/VGPR), then the
// 9-tap x 4-kchunk MFMA loop; taps are pure LDS address shifts.
// A-fragments prefetched 2 deep. XCD pinning: b = blockIdx.x & 7.
// -----------------------------------------------------------------------------
__global__ __launch_bounds__(512, 4) void conv_mfma(const unsigned short* __restrict__ xps,
                                                    const unsigned short* __restrict__ wpk,
                                                    const int* __restrict__ mask_idx,
                                                    float* __restrict__ out) {
    __shared__ char xs[4 * WP * Cn * 2];   // 58368 B, linear (row, wp, slot) 16B chunks

    int b  = blockIdx.x & 7;                // image -> XCD pin
    int lt = blockIdx.x >> 3;               // 0..97
    int l0 = lt * 128;
    int oh0 = l0 / Wn;                      // tile spans output rows oh0, oh0+1

    int tid  = threadIdx.x;
    int wave = tid >> 6, lane = tid & 63;
    int wr = wave >> 2;                     // 0..1 : o block of 32
    int wc = wave & 3;                      // 0..3 : pixel block of 32
    int hi = lane >> 5;

    int lg = l0 + wc * 32 + (lane & 31);    // this lane's pixel
    int oh = lg / Wn, ow = lg - oh * Wn;
    int r  = oh - oh0;                      // 0 or 1
    int mv = mask_idx[lg];

    // ---- Staging: 3648 16B chunks via global_load_lds (linear LDS dest).
    // Wave w owns chunks [w*456, (w+1)*456): 7 full 64-lane calls + 8-lane tail.
    {
        const char* gsrc = (const char*)(xps + ((size_t)(b * HP + oh0) * WP) * Cn);
        int cb0 = wave * 456;
#pragma unroll
        for (int i = 0; i < 8; ++i) {
            int cbase = cb0 + i * 64;
            if (i < 7 || lane < 8) {
                __builtin_amdgcn_global_load_lds(
                    (glob_u32*)(gsrc + ((size_t)(cbase + lane) << 4)),
                    reinterpret_cast<lds_u32*>(reinterpret_cast<uintptr_t>(xs + ((size_t)cbase << 4))),
                    16, 0, 0);
            }
        }
    }

    // A-fragment prefetch for p=0,1 (VGPR loads; waited naturally before use).
    const u32x4* wv = reinterpret_cast<const u32x4*>(wpk);
    u32x4 apre[2][4];
#pragma unroll
    for (int kc = 0; kc < 4; ++kc) apre[0][kc] = wv[(wr * 4 + kc) * 64 + lane];
#pragma unroll
    for (int kc = 0; kc < 4; ++kc) apre[1][kc] = wv[((2 + wr) * 4 + kc) * 64 + lane];

    f32x16 acc = {};
    const u32x4 vzero = {0u, 0u, 0u, 0u};

    __syncthreads();   // drains vmcnt (incl. gload_lds) then barrier

#pragma unroll
    for (int p = 0; p < 9; ++p) {
        int dh = p / 3, dw = p - dh * 3;

        // B-fragments: lane's pixel, 4 k-chunks of 16 channels.
        int wq   = ow + dw;
        int base = ((r + dh) * WP + wq) << 7;
        int swz  = (wq & 7) << 4;
        u32x4 bv[4];
#pragma unroll
        for (int kc = 0; kc < 4; ++kc) {
            int off = (base + ((2 * kc + hi) << 4)) ^ swz;
            bv[kc] = *reinterpret_cast<const u32x4*>(xs + off);
        }
        if (mv == p) { bv[0] = vzero; bv[1] = vzero; bv[2] = vzero; bv[3] = vzero; }

#pragma unroll
        for (int kc = 0; kc < 4; ++kc) {
            bf16x8 a  = *reinterpret_cast<bf16x8*>(&apre[p & 1][kc]);
            bf16x8 bb = *reinterpret_cast<bf16x8*>(&bv[kc]);
            acc = __builtin_amdgcn_mfma_f32_32x32x16_bf16(a, bb, acc, 0, 0, 0);
        }

        // Prefetch p+2's A-fragments into the slot just consumed.
        if (p < 7) {
#pragma unroll
            for (int kc = 0; kc < 4; ++kc)
                apre[p & 1][kc] = wv[(((p + 2) * 2 + wr) * 4 + kc) * 64 + lane];
        }
    }

    // Epilogue: D layout col=lane&31 (=pixel), row=(reg&3)+8*(reg>>2)+4*hi (=o).
    float* ob = out + (size_t)(b * On + wr * 32) * Ln + lg;
#pragma unroll
    for (int reg = 0; reg < 16; ++reg) {
        int orow = (reg & 3) + 8 * (reg >> 2) + 4 * hi;
        ob[(size_t)orow * Ln] = acc[reg];
    }
}

// -----------------------------------------------------------------------------
extern "C" void kernel_launch(void* const* d_in, const int* in_sizes, int n_in,
                              void* d_out, int out_size, void* d_ws, size_t ws_size,
                              hipStream_t stream) {
    const float* x    = (const float*)d_in[0];
    const float* w    = (const float*)d_in[1];
    const int*   mask = (const int*)d_in[2];
    float* out = (float*)d_out;

    unsigned short* xps = (unsigned short*)d_ws;                     // 13,307,904 B
    unsigned short* wpk = (unsigned short*)((char*)d_ws + 13307904); // +73,728 B

    prep_kernel<<<948,     128, 0, stream>>>(x, w, xps, wpk);
    conv_mfma  <<<Bn * 98, 512, 0, stream>>>(xps, wpk, mask, out);
}

// Round 6
// 92.931 us; speedup vs baseline: 1.0516x; 1.0516x over previous
//
#include <hip/hip_runtime.h>
#include <hip/hip_bf16.h>
#include <cstdint>

// Problem constants
#define Bn 8
#define Cn 64
#define Hn 112
#define Wn 112
#define On 64
#define Ln (Hn * Wn)   // 12544
#define HP 114
#define WP 114

typedef __attribute__((ext_vector_type(4)))  float f32x4;
typedef __attribute__((ext_vector_type(16))) float f32x16;
typedef __attribute__((ext_vector_type(8)))  short bf16x8;
typedef __attribute__((ext_vector_type(4)))  unsigned int u32x4;

__device__ __forceinline__ unsigned f2bf(float f) {
    unsigned u = __float_as_uint(f);
    unsigned r = 0x7fffu + ((u >> 16) & 1u);
    return (u + r) >> 16;   // RNE bf16 in low 16 bits
}

// -----------------------------------------------------------------------------
// Kernel 1: weight [O][C][3][3] f32 -> wpk, bf16 in 32x32x16 A-fragment order:
//   frag idx = (p*2 + wr)*4 + kc ; per lane (of 64):
//     o = wr*32 + (lane&31),  c = kc*16 + (lane>>5)*8 + j   (j = 0..7)
// -----------------------------------------------------------------------------
__global__ __launch_bounds__(64) void wpack_kernel(const float* __restrict__ w,
                                                   unsigned short* __restrict__ wpk) {
    int idx = blockIdx.x;             // [0,72) = (p*2 + wr)*4 + kc
    int kc = idx & 3, wr = (idx >> 2) & 1, p = idx >> 3;
    int lane = threadIdx.x;
    int o  = wr * 32 + (lane & 31);
    int cb = kc * 16 + (lane >> 5) * 8;
    unsigned pk[4];
#pragma unroll
    for (int j = 0; j < 4; j++) {
        float v0 = w[((size_t)o * Cn + cb + 2 * j) * 9 + p];
        float v1 = w[((size_t)o * Cn + cb + 2 * j + 1) * 9 + p];
        pk[j] = f2bf(v0) | (f2bf(v1) << 16);
    }
    u32x4 v; v[0] = pk[0]; v[1] = pk[1]; v[2] = pk[2]; v[3] = pk[3];
    reinterpret_cast<u32x4*>(wpk)[idx * 64 + lane] = v;
}

// -----------------------------------------------------------------------------
// Kernel 2: FUSED implicit-GEMM conv, 32x32x16 MFMA, per-pixel tap mask.
// ROW-PAIR TILES: block = 512 thr (8 waves: 2(O) x 4(px)), owns one full
// output row pair (224 px = 7 tiles of 32) x 64 o of one image. Stages the
// same 4 padded input rows as before (58.4 KB) but computes 1.75x the output;
// grid = 448 blocks -> ALL blocks co-resident (2/CU), staging traffic halved.
// Each wave: pass 0 = px-tile wc, pass 1 = px-tile wc+4 (wc=3 idles pass 1).
// Taps are pure LDS address shifts; both-sides XOR swizzle (write & read).
// A-fragments prefetched 2 deep per pass. XCD pinning: b = blockIdx.x & 7.
// -----------------------------------------------------------------------------
__global__ __launch_bounds__(512, 4) void conv_fused(const float* __restrict__ x,
                                                     const unsigned short* __restrict__ wpk,
                                                     const int* __restrict__ mask_idx,
                                                     float* __restrict__ out) {
    __shared__ char xs[4 * WP * Cn * 2];   // 58368 B, [row][wp][c] bf16, 16B-slot swizzle

    int b  = blockIdx.x & 7;                // image -> XCD pin
    int rp = blockIdx.x >> 3;               // 0..55 : output row pair
    int oh0 = rp * 2;

    int tid  = threadIdx.x;
    int wave = tid >> 6, lane = tid & 63;
    int wr = wave >> 2;                     // 0..1 : o block of 32
    int wc = wave & 3;                      // 0..3 : px-tile column
    int hi = lane >> 5;
    int li = lane & 31;

    // ---- Staging: NCHW f32 -> swizzled NHWC bf16 LDS (4 rows oh0-1..oh0+2).
    const float* xb = x + (size_t)b * Cn * Hn * Wn;
#pragma unroll
    for (int it = 0; it < 8; ++it) {
        int q = tid + it * 512;
        if (q < 4 * 8 * WP) {               // 3648 16B chunks
            int row = q / (8 * WP);
            int rem = q - row * (8 * WP);
            int c8  = rem / WP;
            int wp  = rem - c8 * WP;
            int h = oh0 + row - 1;
            int w = wp - 1;
            bool inb = ((unsigned)h < (unsigned)Hn) & ((unsigned)w < (unsigned)Wn);
            const float* s = xb + ((size_t)(c8 * 8) * Hn + (inb ? h : 0)) * Wn + (inb ? w : 0);
            unsigned pk[4];
#pragma unroll
            for (int j = 0; j < 4; ++j) {
                float v0 = s[(size_t)(2 * j)     * (Hn * Wn)];
                float v1 = s[(size_t)(2 * j + 1) * (Hn * Wn)];
                if (!inb) { v0 = 0.f; v1 = 0.f; }
                pk[j] = f2bf(v0) | (f2bf(v1) << 16);
            }
            int qs = (row * WP + wp) * 8 + c8;          // 16B slot index
            int off = (qs * 16) ^ ((wp & 7) << 4);      // write-side swizzle
            u32x4 v; v[0] = pk[0]; v[1] = pk[1]; v[2] = pk[2]; v[3] = pk[3];
            *reinterpret_cast<u32x4*>(xs + off) = v;
        }
    }

    const u32x4* wv = reinterpret_cast<const u32x4*>(wpk);
    const u32x4 vzero = {0u, 0u, 0u, 0u};

    __syncthreads();

#pragma unroll
    for (int pass = 0; pass < 2; ++pass) {
        int tl = wc + pass * 4;             // px-tile 0..6
        if (tl >= 7) break;                 // wave wc=3 idles in pass 1

        int idx = tl * 32 + li;             // 0..223 within the row pair
        int r   = (idx >= Wn) ? 1 : 0;
        int ow  = idx - r * Wn;
        int lg  = oh0 * Wn + idx;           // global pixel in image
        int mv  = mask_idx[lg];

        // A-fragment prefetch, 2 deep (wpk wr-half is L1/L2-hot).
        u32x4 apre[2][4];
#pragma unroll
        for (int kc = 0; kc < 4; ++kc) apre[0][kc] = wv[(wr * 4 + kc) * 64 + lane];
#pragma unroll
        for (int kc = 0; kc < 4; ++kc) apre[1][kc] = wv[((2 + wr) * 4 + kc) * 64 + lane];

        f32x16 acc = {};

#pragma unroll
        for (int p = 0; p < 9; ++p) {
            int dh = p / 3, dw = p - dh * 3;
            int wq   = ow + dw;
            int base = ((r + dh) * WP + wq) << 7;
            int swz  = (wq & 7) << 4;
            u32x4 bv[4];
#pragma unroll
            for (int kc = 0; kc < 4; ++kc) {
                int off = (base + ((2 * kc + hi) << 4)) ^ swz;
                bv[kc] = *reinterpret_cast<const u32x4*>(xs + off);
            }
            if (mv == p) { bv[0] = vzero; bv[1] = vzero; bv[2] = vzero; bv[3] = vzero; }

#pragma unroll
            for (int kc = 0; kc < 4; ++kc) {
                bf16x8 a  = *reinterpret_cast<bf16x8*>(&apre[p & 1][kc]);
                bf16x8 bb = *reinterpret_cast<bf16x8*>(&bv[kc]);
                acc = __builtin_amdgcn_mfma_f32_32x32x16_bf16(a, bb, acc, 0, 0, 0);
            }

            if (p < 7) {
#pragma unroll
                for (int kc = 0; kc < 4; ++kc)
                    apre[p & 1][kc] = wv[(((p + 2) * 2 + wr) * 4 + kc) * 64 + lane];
            }
        }

        // Epilogue: D col=lane&31 (=pixel), row=(reg&3)+8*(reg>>2)+4*hi (=o).
        float* ob = out + (size_t)(b * On + wr * 32) * Ln + lg;
#pragma unroll
        for (int reg = 0; reg < 16; ++reg) {
            int orow = (reg & 3) + 8 * (reg >> 2) + 4 * hi;
            ob[(size_t)orow * Ln] = acc[reg];
        }
    }
}

// -----------------------------------------------------------------------------
extern "C" void kernel_launch(void* const* d_in, const int* in_sizes, int n_in,
                              void* d_out, int out_size, void* d_ws, size_t ws_size,
                              hipStream_t stream) {
    const float* x    = (const float*)d_in[0];
    const float* w    = (const float*)d_in[1];
    const int*   mask = (const int*)d_in[2];
    float* out = (float*)d_out;

    unsigned short* wpk = (unsigned short*)d_ws;   // 73,728 B

    wpack_kernel<<<72,      64,  0, stream>>>(w, wpk);
    conv_fused  <<<Bn * 56, 512, 0, stream>>>(x, wpk, mask, out);
}